// Round 1
// 142.366 us; speedup vs baseline: 1.0039x; 1.0039x over previous
//
#include <hip/hip_runtime.h>
#include <hip/hip_bf16.h>

// MHA fwd: B=2, S=2048, D=256, H=8, Dh=32.
// Outputs: out [2,2048,256] fp32, attn_mean [2,2048,2048] fp32 (concat in d_out).
//
// R8: register software-pipelining of the two S^2 kernels.
// Evidence: R2/R7 (4x exp-cost swings were duration-neutral) => attn_flash /
// attn_write are latency-stall bound, not VALU/trans bound. Fix: prefetch the
// next k-tile (flash) / next head's Q+K frags (write) into registers BEFORE
// computing the current one, so L2 latency (~200cy) hides under the
// MFMA->exp->pack chain. Plus s_setprio(1) around MFMA clusters (T5; applies
// to barrier-free multi-wave attn blocks, m191).

#define B_   2
#define S_   2048
#define D_   256
#define H_   8
#define DH_  32
#define NROW (B_*S_)      // 4096
#define KSPLIT 4
#define KKEYS (S_/KSPLIT) // 512

typedef __attribute__((ext_vector_type(8))) short bf16x8;  // 8 bf16 (4 VGPRs)
typedef __attribute__((ext_vector_type(4))) float f32x4;

__device__ __forceinline__ f32x4 mfma_bf16(bf16x8 a, bf16x8 b, f32x4 c) {
    return __builtin_amdgcn_mfma_f32_16x16x32_bf16(a, b, c, 0, 0, 0);
}

__device__ __forceinline__ float fast_exp2(float x) {
    return __builtin_amdgcn_exp2f(x);   // v_exp_f32
}

__device__ __forceinline__ unsigned short f2bf_bits(float v) {
    __hip_bfloat16 h = __float2bfloat16(v);
    return *reinterpret_cast<unsigned short*>(&h);
}

// fragment-linear index for a row-major [R x 256] matrix element (m, k)
__device__ __forceinline__ size_t fragidx(int m, int k) {
    return (size_t)(m >> 4) * 4096 + (k >> 5) * 512 + ((k >> 3) & 3) * 128
           + (m & 15) * 8 + (k & 7);
}

// ---------------- split fp32 -> (hi, lo) bf16, fragment-linear, one launch ----------------
__global__ void split_all(const float4* __restrict__ x,
                          const float4* __restrict__ wq, const float4* __restrict__ wk,
                          const float4* __restrict__ wv, const float4* __restrict__ wc,
                          ushort4* __restrict__ xh, ushort4* __restrict__ xl,
                          ushort4* __restrict__ wqh, ushort4* __restrict__ wql,
                          ushort4* __restrict__ wkh, ushort4* __restrict__ wkl,
                          ushort4* __restrict__ wvh, ushort4* __restrict__ wvl,
                          ushort4* __restrict__ wch, ushort4* __restrict__ wcl) {
    int i = blockIdx.x * 256 + threadIdx.x;   // total 327680 float4s
    const float4* src; ushort4 *ph, *pl; int off;
    if (i < 262144) { src = x; ph = xh; pl = xl; off = i; }
    else {
        int j = i - 262144;
        int rg = j >> 14; off = j & 16383;
        if (rg == 0)      { src = wq; ph = wqh; pl = wql; }
        else if (rg == 1) { src = wk; ph = wkh; pl = wkl; }
        else if (rg == 2) { src = wv; ph = wvh; pl = wvl; }
        else              { src = wc; ph = wch; pl = wcl; }
    }
    float4 v = src[off];
    float vv[4] = {v.x, v.y, v.z, v.w};
    ushort4 hb, lb;
    unsigned short* hp = (unsigned short*)&hb;
    unsigned short* lp = (unsigned short*)&lb;
    for (int c = 0; c < 4; c++) {
        __hip_bfloat16 h = __float2bfloat16(vv[c]);
        hp[c] = *reinterpret_cast<unsigned short*>(&h);
        lp[c] = f2bf_bits(vv[c] - __bfloat162float(h));
    }
    int m = off >> 6, k = (off & 63) * 4;
    size_t fi = fragidx(m, k);          // divisible by 4
    ph[fi >> 2] = hb;
    pl[fi >> 2] = lb;
}

// ---------------- QKV projection: y = x @ W^T + b ----------------
// grid (NROW/64=64, 4, 3), block 256 (4 waves, 2x2 wave tiles of 32x32).
__global__ __launch_bounds__(256) void qkv_gemm(
    const __hip_bfloat16* __restrict__ xh, const __hip_bfloat16* __restrict__ xl,
    const __hip_bfloat16* __restrict__ w0h, const __hip_bfloat16* __restrict__ w0l,
    const __hip_bfloat16* __restrict__ w1h, const __hip_bfloat16* __restrict__ w1l,
    const __hip_bfloat16* __restrict__ w2h, const __hip_bfloat16* __restrict__ w2l,
    const float* __restrict__ bq, const float* __restrict__ bk, const float* __restrict__ bvv,
    __hip_bfloat16* __restrict__ Qf, __hip_bfloat16* __restrict__ Kf,
    __hip_bfloat16* __restrict__ Vf)
{
    int z = blockIdx.z;
    const __hip_bfloat16* wh = (z==0) ? w0h : (z==1) ? w1h : w2h;
    const __hip_bfloat16* wl = (z==0) ? w0l : (z==1) ? w1l : w2l;
    const float* bias = (z==0) ? bq : (z==1) ? bk : bvv;
    const float sv = (z==0) ? 0.17677669529663687f * 1.4426950408889634f : 1.0f;

    int tid = threadIdx.x;
    int w = tid >> 6, lid = tid & 63, quad = lid >> 4, l15 = lid & 15;
    int row0 = blockIdx.x * 64 + (w >> 1) * 32;
    int col0 = blockIdx.y * 64 + (w & 1) * 32;

    f32x4 acc[2][2] = {};
#pragma unroll
    for (int k0 = 0; k0 < 256; k0 += 32) {
        bf16x8 ah[2], al[2], bh[2], bl[2];
        for (int mi = 0; mi < 2; mi++) {
            size_t ro = (size_t)((row0 + mi * 16) >> 4) * 4096 + (k0 >> 5) * 512 + lid * 8;
            ah[mi] = *(const bf16x8*)(xh + ro);
            al[mi] = *(const bf16x8*)(xl + ro);
        }
        for (int ni = 0; ni < 2; ni++) {
            size_t co = (size_t)((col0 + ni * 16) >> 4) * 4096 + (k0 >> 5) * 512 + lid * 8;
            bh[ni] = *(const bf16x8*)(wh + co);
            bl[ni] = *(const bf16x8*)(wl + co);
        }
        for (int mi = 0; mi < 2; mi++)
            for (int ni = 0; ni < 2; ni++) {
                acc[mi][ni] = mfma_bf16(ah[mi], bh[ni], acc[mi][ni]);
                acc[mi][ni] = mfma_bf16(ah[mi], bl[ni], acc[mi][ni]);
                acc[mi][ni] = mfma_bf16(al[mi], bh[ni], acc[mi][ni]);
            }
    }
    for (int mi = 0; mi < 2; mi++)
        for (int ni = 0; ni < 2; ni++) {
            int col = col0 + ni * 16 + l15;       // D-layout: col = lane&15
            int h = col >> 5, dh = col & 31;
            float bvl = bias[col];
            for (int r = 0; r < 4; r++) {
                int row = row0 + mi * 16 + quad * 4 + r;  // D-layout: row = quad*4+r
                int b = row >> 11, s = row & 2047;
                __hip_bfloat16 o = __float2bfloat16((acc[mi][ni][r] + bvl) * sv);
                size_t bh_base = (size_t)(b * H_ + h) * (S_ * DH_);
                if (z == 2) {
                    int oo = s & 31;
                    int slot = ((oo & 15) >> 2) * 8 + ((oo >> 4) << 2) + (oo & 3);
                    Vf[bh_base + (s >> 5) * 1024 + (dh >> 4) * 512
                       + (slot >> 3) * 128 + (dh & 15) * 8 + (slot & 7)] = o;
                } else {
                    size_t idx = bh_base + (s >> 4) * 512 + (dh >> 3) * 128
                                 + (s & 15) * 8 + (dh & 7);
                    if (z == 0) Qf[idx] = o; else Kf[idx] = o;
                }
            }
        }
}

// ---------------- flash pass: partial l and O' per (b,h,q16,ksplit) ----------------
// grid (S/64=32, H=8, B*KSPLIT=8), block 256 = 4 waves, one q16-tile per wave.
// R8: register double-buffer of K/V tiles; setprio around MFMA clusters.
__global__ __launch_bounds__(256) void attn_flash(
    const __hip_bfloat16* __restrict__ Qf, const __hip_bfloat16* __restrict__ Kf,
    const __hip_bfloat16* __restrict__ Vf,
    float* __restrict__ Opart, float* __restrict__ Lpart)
{
    int tid = threadIdx.x, w = tid >> 6, lid = tid & 63, quad = lid >> 4, l15 = lid & 15;
    int h = blockIdx.y;
    int b = blockIdx.z >> 2, ks = blockIdx.z & 3;
    int q0 = (blockIdx.x * 4 + w) * 16;
    size_t bh_base = (size_t)(b * H_ + h) * (S_ * DH_);
    const __hip_bfloat16* Qp = Qf + bh_base + (q0 >> 4) * 512 + lid * 8;
    const __hip_bfloat16* Kp = Kf + bh_base + lid * 8;
    const __hip_bfloat16* Vp = Vf + bh_base + lid * 8;
    bf16x8 qf = *(const bf16x8*)Qp;                 // B: n=q (lane&15), k=dh
    f32x4 zacc = {};
    f32x4 oacc[2] = {};
    float lp0 = 0.f, lp1 = 0.f;

    int kbeg = ks * KKEYS;
    // prologue prefetch: first k-tile
    bf16x8 kf0 = *(const bf16x8*)(Kp + (kbeg >> 4) * 512);
    bf16x8 kf1 = *(const bf16x8*)(Kp + (kbeg >> 4) * 512 + 512);
    bf16x8 vf0 = *(const bf16x8*)(Vp + (kbeg >> 5) * 1024);
    bf16x8 vf1 = *(const bf16x8*)(Vp + (kbeg >> 5) * 1024 + 512);

#pragma unroll 2
    for (int k0 = kbeg; k0 < kbeg + KKEYS; k0 += 32) {
        bf16x8 ck0 = kf0, ck1 = kf1, cv0 = vf0, cv1 = vf1;
        // prefetch next tile (scalar-guarded wrap on last iter: re-reads kbeg,
        // values unused -> no OOB, no junk-traffic growth beyond one tile)
        int kn = (k0 + 32 < kbeg + KKEYS) ? k0 + 32 : kbeg;
        kf0 = *(const bf16x8*)(Kp + (kn >> 4) * 512);
        kf1 = *(const bf16x8*)(Kp + (kn >> 4) * 512 + 512);
        vf0 = *(const bf16x8*)(Vp + (kn >> 5) * 1024);
        vf1 = *(const bf16x8*)(Vp + (kn >> 5) * 1024 + 512);

        __builtin_amdgcn_s_setprio(1);
        f32x4 c0 = mfma_bf16(ck0, qf, zacc);   // keys k0+quad*4+r, q=l15
        f32x4 c1 = mfma_bf16(ck1, qf, zacc);   // keys k0+16+quad*4+r
        __builtin_amdgcn_s_setprio(0);
        float e0[4], e1[4];
        for (int r = 0; r < 4; r++) {
            e0[r] = fast_exp2(c0[r]);
            e1[r] = fast_exp2(c1[r]);
        }
        lp0 += e0[0] + e0[1] + e0[2] + e0[3];
        lp1 += e1[0] + e1[1] + e1[2] + e1[3];
        union { bf16x8 v; __hip_bfloat162 h2[4]; } pu;
        pu.h2[0] = __float22bfloat162_rn(make_float2(e0[0], e0[1]));
        pu.h2[1] = __float22bfloat162_rn(make_float2(e0[2], e0[3]));
        pu.h2[2] = __float22bfloat162_rn(make_float2(e1[0], e1[1]));
        pu.h2[3] = __float22bfloat162_rn(make_float2(e1[2], e1[3]));
        __builtin_amdgcn_s_setprio(1);
        oacc[0] = mfma_bf16(cv0, pu.v, oacc[0]);   // d 0..15
        oacc[1] = mfma_bf16(cv1, pu.v, oacc[1]);   // d 16..31
        __builtin_amdgcn_s_setprio(0);
    }
    float lp = lp0 + lp1;
    lp += __shfl_xor(lp, 16);
    lp += __shfl_xor(lp, 32);

    size_t base = (size_t)((b * H_ + h) * KSPLIT + ks) * S_;
    if (lid < 16) Lpart[base + q0 + lid] = lp;
    f32x4* op = (f32x4*)(Opart + (base + q0 + l15) * DH_);
    op[quad] = oacc[0];
    op[quad + 4] = oacc[1];
}

// ---------------- combine: ctx = sum(O')/sum(l) -> fragment-linear hi/lo, invL ----------------
__global__ __launch_bounds__(256) void attn_combine(
    const float* __restrict__ Opart, const float* __restrict__ Lpart,
    __hip_bfloat16* __restrict__ cth, __hip_bfloat16* __restrict__ ctl,
    float* __restrict__ invL)
{
    int i = blockIdx.x * 256 + threadIdx.x;   // B*H*S*DH = 1,048,576
    int dh = i & 31;
    int s = (i >> 5) & (S_ - 1);
    int hb = i >> 16;                          // b*H+h in [0,16)
    float l = 0.f, o = 0.f;
#pragma unroll
    for (int ks = 0; ks < KSPLIT; ks++) {
        size_t base = (size_t)(hb * KSPLIT + ks) * S_ + s;
        l += Lpart[base];
        o += Opart[base * DH_ + dh];
    }
    float inv = 1.0f / l;
    float val = o * inv;
    int b = hb >> 3, h = hb & 7;
    size_t fi = fragidx(b * S_ + s, h * DH_ + dh);
    __hip_bfloat16 hv = __float2bfloat16(val);
    cth[fi] = hv;
    ctl[fi] = __float2bfloat16(val - __bfloat162float(hv));
    if (dh == 0) invL[hb * S_ + s] = inv;
}

// ---------------- attn write: head-mean probs, 16q x 256k per block ----------------
// grid (S/256=8, S/16=128, B=2) = 2048 blocks; wave w owns cols k0+w*64..+64.
// R8: rotate Q + 4 K frags across the head loop (prefetch head h+1 before
// computing head h); setprio around the QK MFMA cluster.
__global__ __launch_bounds__(256) void attn_write(
    const __hip_bfloat16* __restrict__ Qf, const __hip_bfloat16* __restrict__ Kf,
    const float* __restrict__ invL, float* __restrict__ attn)
{
    __shared__ float invbuf[H_ * 16];
    int tid = threadIdx.x, w = tid >> 6, lid = tid & 63, quad = lid >> 4, l15 = lid & 15;
    int b = blockIdx.z;
    int q0 = blockIdx.y * 16;
    int k0 = blockIdx.x * 256 + w * 64;
    if (tid < 128) {
        int h = tid >> 4, r = tid & 15;
        invbuf[tid] = invL[(b * H_ + h) * S_ + q0 + r] * 0.125f;  // fold 1/H
    }
    __syncthreads();
    f32x4 zacc = {};
    float psum[4][4] = {};
    size_t bh0 = (size_t)b * H_ * (S_ * DH_);
    size_t qoff = (size_t)(q0 >> 4) * 512 + lid * 8;
    size_t koff = (size_t)(k0 >> 4) * 512 + lid * 8;

    // prologue prefetch: head 0
    bf16x8 qcur = *(const bf16x8*)(Qf + bh0 + qoff);
    bf16x8 kcur0 = *(const bf16x8*)(Kf + bh0 + koff);
    bf16x8 kcur1 = *(const bf16x8*)(Kf + bh0 + koff + 512);
    bf16x8 kcur2 = *(const bf16x8*)(Kf + bh0 + koff + 1024);
    bf16x8 kcur3 = *(const bf16x8*)(Kf + bh0 + koff + 1536);

#pragma unroll 2
    for (int h = 0; h < H_; h++) {
        // prefetch next head (clamped on last iter: redundant cached re-read)
        int hn = (h < H_ - 1) ? h + 1 : h;
        size_t nb = bh0 + (size_t)hn * (S_ * DH_);
        bf16x8 qn = *(const bf16x8*)(Qf + nb + qoff);
        bf16x8 kn0 = *(const bf16x8*)(Kf + nb + koff);
        bf16x8 kn1 = *(const bf16x8*)(Kf + nb + koff + 512);
        bf16x8 kn2 = *(const bf16x8*)(Kf + nb + koff + 1024);
        bf16x8 kn3 = *(const bf16x8*)(Kf + nb + koff + 1536);

        float il[4];
        for (int r = 0; r < 4; r++) il[r] = invbuf[h * 16 + quad * 4 + r];

        __builtin_amdgcn_s_setprio(1);
        f32x4 c0 = mfma_bf16(qcur, kcur0, zacc);  // C: row=q (quad*4+r), col=key (l15)
        f32x4 c1 = mfma_bf16(qcur, kcur1, zacc);
        f32x4 c2 = mfma_bf16(qcur, kcur2, zacc);
        f32x4 c3 = mfma_bf16(qcur, kcur3, zacc);
        __builtin_amdgcn_s_setprio(0);
        for (int r = 0; r < 4; r++) {
            psum[0][r] += fast_exp2(c0[r]) * il[r];
            psum[1][r] += fast_exp2(c1[r]) * il[r];
            psum[2][r] += fast_exp2(c2[r]) * il[r];
            psum[3][r] += fast_exp2(c3[r]) * il[r];
        }
        qcur = qn;
        kcur0 = kn0; kcur1 = kn1; kcur2 = kn2; kcur3 = kn3;
    }
    for (int nt = 0; nt < 4; nt++)
        for (int r = 0; r < 4; r++)
            attn[(size_t)(b * S_ + q0 + quad * 4 + r) * S_ + k0 + nt * 16 + l15] =
                psum[nt][r];
}

// ---------------- output projection: out = ctx @ wc^T + bc (fp32 out) ----------------
// grid (NROW/64=64, 4), block 256 (4 waves, 2x2 wave tiles of 32x32).
__global__ __launch_bounds__(256) void out_gemm(
    const __hip_bfloat16* __restrict__ ch, const __hip_bfloat16* __restrict__ cl,
    const __hip_bfloat16* __restrict__ wh, const __hip_bfloat16* __restrict__ wl,
    const float* __restrict__ bias, float* __restrict__ out)
{
    int tid = threadIdx.x;
    int w = tid >> 6, lid = tid & 63, quad = lid >> 4, l15 = lid & 15;
    int row0 = blockIdx.x * 64 + (w >> 1) * 32;
    int col0 = blockIdx.y * 64 + (w & 1) * 32;

    f32x4 acc[2][2] = {};
#pragma unroll
    for (int k0 = 0; k0 < 256; k0 += 32) {
        bf16x8 ah[2], al[2], bh[2], bl[2];
        for (int mi = 0; mi < 2; mi++) {
            size_t ro = (size_t)((row0 + mi * 16) >> 4) * 4096 + (k0 >> 5) * 512 + lid * 8;
            ah[mi] = *(const bf16x8*)(ch + ro);
            al[mi] = *(const bf16x8*)(cl + ro);
        }
        for (int ni = 0; ni < 2; ni++) {
            size_t co = (size_t)((col0 + ni * 16) >> 4) * 4096 + (k0 >> 5) * 512 + lid * 8;
            bh[ni] = *(const bf16x8*)(wh + co);
            bl[ni] = *(const bf16x8*)(wl + co);
        }
        for (int mi = 0; mi < 2; mi++)
            for (int ni = 0; ni < 2; ni++) {
                acc[mi][ni] = mfma_bf16(ah[mi], bh[ni], acc[mi][ni]);
                acc[mi][ni] = mfma_bf16(ah[mi], bl[ni], acc[mi][ni]);
                acc[mi][ni] = mfma_bf16(al[mi], bh[ni], acc[mi][ni]);
            }
    }
    for (int mi = 0; mi < 2; mi++)
        for (int ni = 0; ni < 2; ni++) {
            int col = col0 + ni * 16 + l15;
            float bvl = bias[col];
            for (int r = 0; r < 4; r++) {
                int row = row0 + mi * 16 + quad * 4 + r;
                out[(size_t)row * 256 + col] = acc[mi][ni][r] + bvl;
            }
        }
}

extern "C" void kernel_launch(void* const* d_in, const int* in_sizes, int n_in,
                              void* d_out, int out_size, void* d_ws, size_t ws_size,
                              hipStream_t stream) {
    const float* x  = (const float*)d_in[0];
    const float* wq = (const float*)d_in[1];
    const float* bq = (const float*)d_in[2];
    const float* wk = (const float*)d_in[3];
    const float* bk = (const float*)d_in[4];
    const float* wv = (const float*)d_in[5];
    const float* bv = (const float*)d_in[6];
    const float* wc = (const float*)d_in[7];
    const float* bc = (const float*)d_in[8];

    char* ws = (char*)d_ws;
    const size_t MB = 1u << 20;
    const size_t KB128 = 128u * 1024u;
    __hip_bfloat16* xh  = (__hip_bfloat16*)(ws + 0 * MB);
    __hip_bfloat16* xl  = (__hip_bfloat16*)(ws + 2 * MB);
    __hip_bfloat16* wqh = (__hip_bfloat16*)(ws + 4 * MB + 0 * KB128);
    __hip_bfloat16* wql = (__hip_bfloat16*)(ws + 4 * MB + 1 * KB128);
    __hip_bfloat16* wkh = (__hip_bfloat16*)(ws + 4 * MB + 2 * KB128);
    __hip_bfloat16* wkl = (__hip_bfloat16*)(ws + 4 * MB + 3 * KB128);
    __hip_bfloat16* wvh = (__hip_bfloat16*)(ws + 4 * MB + 4 * KB128);
    __hip_bfloat16* wvl = (__hip_bfloat16*)(ws + 4 * MB + 5 * KB128);
    __hip_bfloat16* wch = (__hip_bfloat16*)(ws + 4 * MB + 6 * KB128);
    __hip_bfloat16* wcl = (__hip_bfloat16*)(ws + 4 * MB + 7 * KB128);
    __hip_bfloat16* Qfb = (__hip_bfloat16*)(ws + 5 * MB);
    __hip_bfloat16* Kfb = (__hip_bfloat16*)(ws + 7 * MB);
    __hip_bfloat16* Vfb = (__hip_bfloat16*)(ws + 9 * MB);
    __hip_bfloat16* cth = (__hip_bfloat16*)(ws + 11 * MB);
    __hip_bfloat16* ctl = (__hip_bfloat16*)(ws + 13 * MB);
    float* Opart = (float*)(ws + 15 * MB);                    // 16 MB (KSPLIT=4)
    float* Lpart = (float*)(ws + 31 * MB);                    // 512 KB
    float* invL  = (float*)(ws + 31 * MB + 512 * 1024);       // 128 KB

    float* outp  = (float*)d_out;
    float* attnp = outp + (size_t)NROW * D_;  // outputs concatenated: out, attention

    hipLaunchKernelGGL(split_all, dim3(1280), dim3(256), 0, stream,
                       (const float4*)x, (const float4*)wq, (const float4*)wk,
                       (const float4*)wv, (const float4*)wc,
                       (ushort4*)xh, (ushort4*)xl,
                       (ushort4*)wqh, (ushort4*)wql, (ushort4*)wkh, (ushort4*)wkl,
                       (ushort4*)wvh, (ushort4*)wvl, (ushort4*)wch, (ushort4*)wcl);

    hipLaunchKernelGGL(qkv_gemm, dim3(NROW / 64, 4, 3), dim3(256), 0, stream,
                       xh, xl, wqh, wql, wkh, wkl, wvh, wvl, bq, bk, bv, Qfb, Kfb, Vfb);

    hipLaunchKernelGGL(attn_flash, dim3(S_ / 64, H_, B_ * KSPLIT), dim3(256), 0, stream,
                       Qfb, Kfb, Vfb, Opart, Lpart);

    hipLaunchKernelGGL(attn_combine, dim3(4096), dim3(256), 0, stream,
                       Opart, Lpart, cth, ctl, invL);

    hipLaunchKernelGGL(attn_write, dim3(S_ / 256, S_ / 16, B_), dim3(256), 0, stream,
                       Qfb, Kfb, invL, attnp);

    hipLaunchKernelGGL(out_gemm, dim3(NROW / 64, 4), dim3(256), 0, stream,
                       cth, ctl, wch, wcl, bc, outp);
}

// Round 2
// 135.617 us; speedup vs baseline: 1.0539x; 1.0498x over previous
//
#include <hip/hip_runtime.h>
#include <hip/hip_bf16.h>

// MHA fwd: B=2, S=2048, D=256, H=8, Dh=32.
// Outputs: out [2,2048,256] fp32, attn_mean [2,2048,2048] fp32 (concat in d_out).
//
// R9: pipeline restructure 6 launches -> 4.
// Evidence: R2/R6/R7/R8 all neutral => in-loop edits don't move total time;
// cost must be inter-kernel (launch+drain overhead, partials round-trip).
// attn_flash now block-combines its 4 k-split waves in LDS and writes the
// normalized context (cth/ctl) + invL directly: attn_combine kernel, Opart
// (16MB write + 16MB read) and Lpart are eliminated. attn_write and out_gemm
// (independent) merge into one launch, out_gemm blocks first to hide in the
// attn tail.

#define B_   2
#define S_   2048
#define D_   256
#define H_   8
#define DH_  32
#define NROW (B_*S_)      // 4096
#define KSPLIT 4
#define KKEYS (S_/KSPLIT) // 512

typedef __attribute__((ext_vector_type(8))) short bf16x8;  // 8 bf16 (4 VGPRs)
typedef __attribute__((ext_vector_type(4))) float f32x4;

__device__ __forceinline__ f32x4 mfma_bf16(bf16x8 a, bf16x8 b, f32x4 c) {
    return __builtin_amdgcn_mfma_f32_16x16x32_bf16(a, b, c, 0, 0, 0);
}

__device__ __forceinline__ float fast_exp2(float x) {
    return __builtin_amdgcn_exp2f(x);   // v_exp_f32
}

__device__ __forceinline__ unsigned short f2bf_bits(float v) {
    __hip_bfloat16 h = __float2bfloat16(v);
    return *reinterpret_cast<unsigned short*>(&h);
}

// fragment-linear index for a row-major [R x 256] matrix element (m, k)
__device__ __forceinline__ size_t fragidx(int m, int k) {
    return (size_t)(m >> 4) * 4096 + (k >> 5) * 512 + ((k >> 3) & 3) * 128
           + (m & 15) * 8 + (k & 7);
}

// ---------------- split fp32 -> (hi, lo) bf16, fragment-linear, one launch ----------------
__global__ void split_all(const float4* __restrict__ x,
                          const float4* __restrict__ wq, const float4* __restrict__ wk,
                          const float4* __restrict__ wv, const float4* __restrict__ wc,
                          ushort4* __restrict__ xh, ushort4* __restrict__ xl,
                          ushort4* __restrict__ wqh, ushort4* __restrict__ wql,
                          ushort4* __restrict__ wkh, ushort4* __restrict__ wkl,
                          ushort4* __restrict__ wvh, ushort4* __restrict__ wvl,
                          ushort4* __restrict__ wch, ushort4* __restrict__ wcl) {
    int i = blockIdx.x * 256 + threadIdx.x;   // total 327680 float4s
    const float4* src; ushort4 *ph, *pl; int off;
    if (i < 262144) { src = x; ph = xh; pl = xl; off = i; }
    else {
        int j = i - 262144;
        int rg = j >> 14; off = j & 16383;
        if (rg == 0)      { src = wq; ph = wqh; pl = wql; }
        else if (rg == 1) { src = wk; ph = wkh; pl = wkl; }
        else if (rg == 2) { src = wv; ph = wvh; pl = wvl; }
        else              { src = wc; ph = wch; pl = wcl; }
    }
    float4 v = src[off];
    float vv[4] = {v.x, v.y, v.z, v.w};
    ushort4 hb, lb;
    unsigned short* hp = (unsigned short*)&hb;
    unsigned short* lp = (unsigned short*)&lb;
    for (int c = 0; c < 4; c++) {
        __hip_bfloat16 h = __float2bfloat16(vv[c]);
        hp[c] = *reinterpret_cast<unsigned short*>(&h);
        lp[c] = f2bf_bits(vv[c] - __bfloat162float(h));
    }
    int m = off >> 6, k = (off & 63) * 4;
    size_t fi = fragidx(m, k);          // divisible by 4
    ph[fi >> 2] = hb;
    pl[fi >> 2] = lb;
}

// ---------------- QKV projection: y = x @ W^T + b ----------------
// grid (NROW/64=64, 4, 3), block 256 (4 waves, 2x2 wave tiles of 32x32).
__global__ __launch_bounds__(256) void qkv_gemm(
    const __hip_bfloat16* __restrict__ xh, const __hip_bfloat16* __restrict__ xl,
    const __hip_bfloat16* __restrict__ w0h, const __hip_bfloat16* __restrict__ w0l,
    const __hip_bfloat16* __restrict__ w1h, const __hip_bfloat16* __restrict__ w1l,
    const __hip_bfloat16* __restrict__ w2h, const __hip_bfloat16* __restrict__ w2l,
    const float* __restrict__ bq, const float* __restrict__ bk, const float* __restrict__ bvv,
    __hip_bfloat16* __restrict__ Qf, __hip_bfloat16* __restrict__ Kf,
    __hip_bfloat16* __restrict__ Vf)
{
    int z = blockIdx.z;
    const __hip_bfloat16* wh = (z==0) ? w0h : (z==1) ? w1h : w2h;
    const __hip_bfloat16* wl = (z==0) ? w0l : (z==1) ? w1l : w2l;
    const float* bias = (z==0) ? bq : (z==1) ? bk : bvv;
    const float sv = (z==0) ? 0.17677669529663687f * 1.4426950408889634f : 1.0f;

    int tid = threadIdx.x;
    int w = tid >> 6, lid = tid & 63, quad = lid >> 4, l15 = lid & 15;
    int row0 = blockIdx.x * 64 + (w >> 1) * 32;
    int col0 = blockIdx.y * 64 + (w & 1) * 32;

    f32x4 acc[2][2] = {};
#pragma unroll
    for (int k0 = 0; k0 < 256; k0 += 32) {
        bf16x8 ah[2], al[2], bh[2], bl[2];
        for (int mi = 0; mi < 2; mi++) {
            size_t ro = (size_t)((row0 + mi * 16) >> 4) * 4096 + (k0 >> 5) * 512 + lid * 8;
            ah[mi] = *(const bf16x8*)(xh + ro);
            al[mi] = *(const bf16x8*)(xl + ro);
        }
        for (int ni = 0; ni < 2; ni++) {
            size_t co = (size_t)((col0 + ni * 16) >> 4) * 4096 + (k0 >> 5) * 512 + lid * 8;
            bh[ni] = *(const bf16x8*)(wh + co);
            bl[ni] = *(const bf16x8*)(wl + co);
        }
        for (int mi = 0; mi < 2; mi++)
            for (int ni = 0; ni < 2; ni++) {
                acc[mi][ni] = mfma_bf16(ah[mi], bh[ni], acc[mi][ni]);
                acc[mi][ni] = mfma_bf16(ah[mi], bl[ni], acc[mi][ni]);
                acc[mi][ni] = mfma_bf16(al[mi], bh[ni], acc[mi][ni]);
            }
    }
    for (int mi = 0; mi < 2; mi++)
        for (int ni = 0; ni < 2; ni++) {
            int col = col0 + ni * 16 + l15;       // D-layout: col = lane&15
            int h = col >> 5, dh = col & 31;
            float bvl = bias[col];
            for (int r = 0; r < 4; r++) {
                int row = row0 + mi * 16 + quad * 4 + r;  // D-layout: row = quad*4+r
                int b = row >> 11, s = row & 2047;
                __hip_bfloat16 o = __float2bfloat16((acc[mi][ni][r] + bvl) * sv);
                size_t bh_base = (size_t)(b * H_ + h) * (S_ * DH_);
                if (z == 2) {
                    int oo = s & 31;
                    int slot = ((oo & 15) >> 2) * 8 + ((oo >> 4) << 2) + (oo & 3);
                    Vf[bh_base + (s >> 5) * 1024 + (dh >> 4) * 512
                       + (slot >> 3) * 128 + (dh & 15) * 8 + (slot & 7)] = o;
                } else {
                    size_t idx = bh_base + (s >> 4) * 512 + (dh >> 3) * 128
                                 + (s & 15) * 8 + (dh & 7);
                    if (z == 0) Qf[idx] = o; else Kf[idx] = o;
                }
            }
        }
}

// ---------------- flash pass, fused combine ----------------
// grid (S/16=128, H=8, B=2) = 2048 blocks, block 256 = 4 waves.
// One q16-tile per BLOCK; wave w handles keys w*512..+511. Partial l / O'
// combined in LDS, normalized, written as fragment-linear hi/lo ctx + invL.
__global__ __launch_bounds__(256) void attn_flash(
    const __hip_bfloat16* __restrict__ Qf, const __hip_bfloat16* __restrict__ Kf,
    const __hip_bfloat16* __restrict__ Vf,
    __hip_bfloat16* __restrict__ cth, __hip_bfloat16* __restrict__ ctl,
    float* __restrict__ invL)
{
    __shared__ float sO[KSPLIT][16][33];   // +1 pad: avoid bank conflicts
    __shared__ float sL[KSPLIT][16];
    int tid = threadIdx.x, w = tid >> 6, lid = tid & 63, quad = lid >> 4, l15 = lid & 15;
    int h = blockIdx.y;
    int b = blockIdx.z;
    int q0 = blockIdx.x * 16;
    size_t bh_base = (size_t)(b * H_ + h) * (S_ * DH_);
    const __hip_bfloat16* Qp = Qf + bh_base + (q0 >> 4) * 512 + lid * 8;
    const __hip_bfloat16* Kp = Kf + bh_base + lid * 8;
    const __hip_bfloat16* Vp = Vf + bh_base + lid * 8;
    bf16x8 qf = *(const bf16x8*)Qp;                 // B: n=q (lane&15), k=dh
    f32x4 zacc = {};
    f32x4 oacc[2] = {};
    float lp0 = 0.f, lp1 = 0.f;

    int kbeg = w * KKEYS;
    // prologue prefetch: first k-tile
    bf16x8 kf0 = *(const bf16x8*)(Kp + (kbeg >> 4) * 512);
    bf16x8 kf1 = *(const bf16x8*)(Kp + (kbeg >> 4) * 512 + 512);
    bf16x8 vf0 = *(const bf16x8*)(Vp + (kbeg >> 5) * 1024);
    bf16x8 vf1 = *(const bf16x8*)(Vp + (kbeg >> 5) * 1024 + 512);

#pragma unroll 2
    for (int k0 = kbeg; k0 < kbeg + KKEYS; k0 += 32) {
        bf16x8 ck0 = kf0, ck1 = kf1, cv0 = vf0, cv1 = vf1;
        // prefetch next tile (wrap-clamped on last iter; value unused)
        int kn = (k0 + 32 < kbeg + KKEYS) ? k0 + 32 : kbeg;
        kf0 = *(const bf16x8*)(Kp + (kn >> 4) * 512);
        kf1 = *(const bf16x8*)(Kp + (kn >> 4) * 512 + 512);
        vf0 = *(const bf16x8*)(Vp + (kn >> 5) * 1024);
        vf1 = *(const bf16x8*)(Vp + (kn >> 5) * 1024 + 512);

        __builtin_amdgcn_s_setprio(1);
        f32x4 c0 = mfma_bf16(ck0, qf, zacc);   // keys k0+quad*4+r, q=l15
        f32x4 c1 = mfma_bf16(ck1, qf, zacc);   // keys k0+16+quad*4+r
        __builtin_amdgcn_s_setprio(0);
        float e0[4], e1[4];
        for (int r = 0; r < 4; r++) {
            e0[r] = fast_exp2(c0[r]);
            e1[r] = fast_exp2(c1[r]);
        }
        lp0 += e0[0] + e0[1] + e0[2] + e0[3];
        lp1 += e1[0] + e1[1] + e1[2] + e1[3];
        union { bf16x8 v; __hip_bfloat162 h2[4]; } pu;
        pu.h2[0] = __float22bfloat162_rn(make_float2(e0[0], e0[1]));
        pu.h2[1] = __float22bfloat162_rn(make_float2(e0[2], e0[3]));
        pu.h2[2] = __float22bfloat162_rn(make_float2(e1[0], e1[1]));
        pu.h2[3] = __float22bfloat162_rn(make_float2(e1[2], e1[3]));
        __builtin_amdgcn_s_setprio(1);
        oacc[0] = mfma_bf16(cv0, pu.v, oacc[0]);   // d 0..15
        oacc[1] = mfma_bf16(cv1, pu.v, oacc[1]);   // d 16..31
        __builtin_amdgcn_s_setprio(0);
    }
    float lp = lp0 + lp1;
    lp += __shfl_xor(lp, 16);
    lp += __shfl_xor(lp, 32);   // every lane: full 512-key row sum for q=l15

    // stash partials in LDS
    for (int r = 0; r < 4; r++) {
        sO[w][l15][quad * 4 + r]      = oacc[0][r];
        sO[w][l15][16 + quad * 4 + r] = oacc[1][r];
    }
    if (lid < 16) sL[w][lid] = lp;
    __syncthreads();

    // combine + normalize + write: 512 ctx elems / 256 threads = 2 each
    int d = tid & 31, q = tid >> 5;   // q in 0..7
#pragma unroll
    for (int qq = q; qq < 16; qq += 8) {
        float l = sL[0][qq] + sL[1][qq] + sL[2][qq] + sL[3][qq];
        float o = sO[0][qq][d] + sO[1][qq][d] + sO[2][qq][d] + sO[3][qq][d];
        float inv = 1.0f / l;
        float val = o * inv;
        size_t fi = fragidx(b * S_ + q0 + qq, h * DH_ + d);
        __hip_bfloat16 hv = __float2bfloat16(val);
        cth[fi] = hv;
        ctl[fi] = __float2bfloat16(val - __bfloat162float(hv));
        if (d == 0) invL[(b * H_ + h) * S_ + q0 + qq] = inv;
    }
}

// ---------------- merged: out projection (blocks 0..255) + attn write (256..2303) ----
// out_gemm first so its 256 blocks overlap the attn wave instead of the tail.
__global__ __launch_bounds__(256) void attn_out(
    const __hip_bfloat16* __restrict__ Qf, const __hip_bfloat16* __restrict__ Kf,
    const float* __restrict__ invL,
    const __hip_bfloat16* __restrict__ ch, const __hip_bfloat16* __restrict__ cl,
    const __hip_bfloat16* __restrict__ wh, const __hip_bfloat16* __restrict__ wl,
    const float* __restrict__ bias,
    float* __restrict__ attn, float* __restrict__ out)
{
    __shared__ float invbuf[H_ * 16];
    int bid = blockIdx.x;
    int tid = threadIdx.x, w = tid >> 6, lid = tid & 63, quad = lid >> 4, l15 = lid & 15;

    if (bid < 256) {
        // ---- out_gemm: out = ctx @ wc^T + bc (fp32 out), 2x2 wave tiles of 32x32 ----
        int row0 = (bid & 63) * 64 + (w >> 1) * 32;
        int col0 = (bid >> 6) * 64 + (w & 1) * 32;

        f32x4 acc[2][2] = {};
#pragma unroll
        for (int k0 = 0; k0 < 256; k0 += 32) {
            bf16x8 ah[2], al[2], bh[2], bl[2];
            for (int mi = 0; mi < 2; mi++) {
                size_t ro = (size_t)((row0 + mi * 16) >> 4) * 4096 + (k0 >> 5) * 512 + lid * 8;
                ah[mi] = *(const bf16x8*)(ch + ro);
                al[mi] = *(const bf16x8*)(cl + ro);
            }
            for (int ni = 0; ni < 2; ni++) {
                size_t co = (size_t)((col0 + ni * 16) >> 4) * 4096 + (k0 >> 5) * 512 + lid * 8;
                bh[ni] = *(const bf16x8*)(wh + co);
                bl[ni] = *(const bf16x8*)(wl + co);
            }
            for (int mi = 0; mi < 2; mi++)
                for (int ni = 0; ni < 2; ni++) {
                    acc[mi][ni] = mfma_bf16(ah[mi], bh[ni], acc[mi][ni]);
                    acc[mi][ni] = mfma_bf16(ah[mi], bl[ni], acc[mi][ni]);
                    acc[mi][ni] = mfma_bf16(al[mi], bh[ni], acc[mi][ni]);
                }
        }
        for (int mi = 0; mi < 2; mi++)
            for (int ni = 0; ni < 2; ni++) {
                int col = col0 + ni * 16 + l15;
                float bvl = bias[col];
                for (int r = 0; r < 4; r++) {
                    int row = row0 + mi * 16 + quad * 4 + r;
                    out[(size_t)row * 256 + col] = acc[mi][ni][r] + bvl;
                }
            }
    } else {
        // ---- attn write: head-mean probs, 16q x 256k per block ----
        int ab = bid - 256;
        int kx = ab & 7, qy = (ab >> 3) & 127, b = ab >> 10;
        int q0 = qy * 16;
        int k0 = kx * 256 + w * 64;
        if (tid < 128) {
            int h = tid >> 4, r = tid & 15;
            invbuf[tid] = invL[(b * H_ + h) * S_ + q0 + r] * 0.125f;  // fold 1/H
        }
        __syncthreads();
        f32x4 zacc = {};
        float psum[4][4] = {};
        size_t bh0 = (size_t)b * H_ * (S_ * DH_);
        size_t qoff = (size_t)(q0 >> 4) * 512 + lid * 8;
        size_t koff = (size_t)(k0 >> 4) * 512 + lid * 8;

        // prologue prefetch: head 0
        bf16x8 qcur = *(const bf16x8*)(Qf + bh0 + qoff);
        bf16x8 kcur0 = *(const bf16x8*)(Kf + bh0 + koff);
        bf16x8 kcur1 = *(const bf16x8*)(Kf + bh0 + koff + 512);
        bf16x8 kcur2 = *(const bf16x8*)(Kf + bh0 + koff + 1024);
        bf16x8 kcur3 = *(const bf16x8*)(Kf + bh0 + koff + 1536);

#pragma unroll 2
        for (int h = 0; h < H_; h++) {
            int hn = (h < H_ - 1) ? h + 1 : h;
            size_t nb = bh0 + (size_t)hn * (S_ * DH_);
            bf16x8 qn = *(const bf16x8*)(Qf + nb + qoff);
            bf16x8 kn0 = *(const bf16x8*)(Kf + nb + koff);
            bf16x8 kn1 = *(const bf16x8*)(Kf + nb + koff + 512);
            bf16x8 kn2 = *(const bf16x8*)(Kf + nb + koff + 1024);
            bf16x8 kn3 = *(const bf16x8*)(Kf + nb + koff + 1536);

            float il[4];
            for (int r = 0; r < 4; r++) il[r] = invbuf[h * 16 + quad * 4 + r];

            __builtin_amdgcn_s_setprio(1);
            f32x4 c0 = mfma_bf16(qcur, kcur0, zacc);  // C: row=q (quad*4+r), col=key (l15)
            f32x4 c1 = mfma_bf16(qcur, kcur1, zacc);
            f32x4 c2 = mfma_bf16(qcur, kcur2, zacc);
            f32x4 c3 = mfma_bf16(qcur, kcur3, zacc);
            __builtin_amdgcn_s_setprio(0);
            for (int r = 0; r < 4; r++) {
                psum[0][r] += fast_exp2(c0[r]) * il[r];
                psum[1][r] += fast_exp2(c1[r]) * il[r];
                psum[2][r] += fast_exp2(c2[r]) * il[r];
                psum[3][r] += fast_exp2(c3[r]) * il[r];
            }
            qcur = qn;
            kcur0 = kn0; kcur1 = kn1; kcur2 = kn2; kcur3 = kn3;
        }
        for (int nt = 0; nt < 4; nt++)
            for (int r = 0; r < 4; r++)
                attn[(size_t)(b * S_ + q0 + quad * 4 + r) * S_ + k0 + nt * 16 + l15] =
                    psum[nt][r];
    }
}

extern "C" void kernel_launch(void* const* d_in, const int* in_sizes, int n_in,
                              void* d_out, int out_size, void* d_ws, size_t ws_size,
                              hipStream_t stream) {
    const float* x  = (const float*)d_in[0];
    const float* wq = (const float*)d_in[1];
    const float* bq = (const float*)d_in[2];
    const float* wk = (const float*)d_in[3];
    const float* bk = (const float*)d_in[4];
    const float* wv = (const float*)d_in[5];
    const float* bv = (const float*)d_in[6];
    const float* wc = (const float*)d_in[7];
    const float* bc = (const float*)d_in[8];

    char* ws = (char*)d_ws;
    const size_t MB = 1u << 20;
    const size_t KB128 = 128u * 1024u;
    __hip_bfloat16* xh  = (__hip_bfloat16*)(ws + 0 * MB);
    __hip_bfloat16* xl  = (__hip_bfloat16*)(ws + 2 * MB);
    __hip_bfloat16* wqh = (__hip_bfloat16*)(ws + 4 * MB + 0 * KB128);
    __hip_bfloat16* wql = (__hip_bfloat16*)(ws + 4 * MB + 1 * KB128);
    __hip_bfloat16* wkh = (__hip_bfloat16*)(ws + 4 * MB + 2 * KB128);
    __hip_bfloat16* wkl = (__hip_bfloat16*)(ws + 4 * MB + 3 * KB128);
    __hip_bfloat16* wvh = (__hip_bfloat16*)(ws + 4 * MB + 4 * KB128);
    __hip_bfloat16* wvl = (__hip_bfloat16*)(ws + 4 * MB + 5 * KB128);
    __hip_bfloat16* wch = (__hip_bfloat16*)(ws + 4 * MB + 6 * KB128);
    __hip_bfloat16* wcl = (__hip_bfloat16*)(ws + 4 * MB + 7 * KB128);
    __hip_bfloat16* Qfb = (__hip_bfloat16*)(ws + 5 * MB);
    __hip_bfloat16* Kfb = (__hip_bfloat16*)(ws + 7 * MB);
    __hip_bfloat16* Vfb = (__hip_bfloat16*)(ws + 9 * MB);
    __hip_bfloat16* cth = (__hip_bfloat16*)(ws + 11 * MB);
    __hip_bfloat16* ctl = (__hip_bfloat16*)(ws + 13 * MB);
    float* invL  = (float*)(ws + 15 * MB);                    // 128 KB

    float* outp  = (float*)d_out;
    float* attnp = outp + (size_t)NROW * D_;  // outputs concatenated: out, attention

    hipLaunchKernelGGL(split_all, dim3(1280), dim3(256), 0, stream,
                       (const float4*)x, (const float4*)wq, (const float4*)wk,
                       (const float4*)wv, (const float4*)wc,
                       (ushort4*)xh, (ushort4*)xl,
                       (ushort4*)wqh, (ushort4*)wql, (ushort4*)wkh, (ushort4*)wkl,
                       (ushort4*)wvh, (ushort4*)wvl, (ushort4*)wch, (ushort4*)wcl);

    hipLaunchKernelGGL(qkv_gemm, dim3(NROW / 64, 4, 3), dim3(256), 0, stream,
                       xh, xl, wqh, wql, wkh, wkl, wvh, wvl, bq, bk, bv, Qfb, Kfb, Vfb);

    hipLaunchKernelGGL(attn_flash, dim3(S_ / 16, H_, B_), dim3(256), 0, stream,
                       Qfb, Kfb, Vfb, cth, ctl, invL);

    hipLaunchKernelGGL(attn_out, dim3(256 + 2048), dim3(256), 0, stream,
                       Qfb, Kfb, invL, cth, ctl, wch, wcl, bc, attnp, outp);
}

// Round 3
// 134.203 us; speedup vs baseline: 1.0650x; 1.0105x over previous
//
#include <hip/hip_runtime.h>
#include <hip/hip_bf16.h>

// MHA fwd: B=2, S=2048, D=256, H=8, Dh=32.
// Outputs: out [2,2048,256] fp32, attn_mean [2,2048,2048] fp32 (concat in d_out).
//
// R10: XCD-chunked block swizzle (T1) on the two S^2 kernels.
// Evidence: R9 showed launches ~0.75us each (fusion saved only traffic);
// ~85us remains unexplained by MFMA/exp/HBM floors. Theory: K/V re-reads
// (268 MB in flash, ~270 MB in attn) thrash L2 because the default
// round-robin dispatch replicates each (b,h) K/V slice into all 8 XCD L2s
// (8 x 12 MB footprint >> 32 MB). Chunked swizzle g=(f&7)*256+(f>>3) gives
// each XCD a contiguous block range sharing K/V (512KB-1.3MB working set,
// L2-resident). Bijective (2048 % 8 == 0). No math/layout changes.

#define B_   2
#define S_   2048
#define D_   256
#define H_   8
#define DH_  32
#define NROW (B_*S_)      // 4096
#define KSPLIT 4
#define KKEYS (S_/KSPLIT) // 512

typedef __attribute__((ext_vector_type(8))) short bf16x8;  // 8 bf16 (4 VGPRs)
typedef __attribute__((ext_vector_type(4))) float f32x4;

__device__ __forceinline__ f32x4 mfma_bf16(bf16x8 a, bf16x8 b, f32x4 c) {
    return __builtin_amdgcn_mfma_f32_16x16x32_bf16(a, b, c, 0, 0, 0);
}

__device__ __forceinline__ float fast_exp2(float x) {
    return __builtin_amdgcn_exp2f(x);   // v_exp_f32
}

__device__ __forceinline__ unsigned short f2bf_bits(float v) {
    __hip_bfloat16 h = __float2bfloat16(v);
    return *reinterpret_cast<unsigned short*>(&h);
}

// fragment-linear index for a row-major [R x 256] matrix element (m, k)
__device__ __forceinline__ size_t fragidx(int m, int k) {
    return (size_t)(m >> 4) * 4096 + (k >> 5) * 512 + ((k >> 3) & 3) * 128
           + (m & 15) * 8 + (k & 7);
}

// ---------------- split fp32 -> (hi, lo) bf16, fragment-linear, one launch ----------------
__global__ void split_all(const float4* __restrict__ x,
                          const float4* __restrict__ wq, const float4* __restrict__ wk,
                          const float4* __restrict__ wv, const float4* __restrict__ wc,
                          ushort4* __restrict__ xh, ushort4* __restrict__ xl,
                          ushort4* __restrict__ wqh, ushort4* __restrict__ wql,
                          ushort4* __restrict__ wkh, ushort4* __restrict__ wkl,
                          ushort4* __restrict__ wvh, ushort4* __restrict__ wvl,
                          ushort4* __restrict__ wch, ushort4* __restrict__ wcl) {
    int i = blockIdx.x * 256 + threadIdx.x;   // total 327680 float4s
    const float4* src; ushort4 *ph, *pl; int off;
    if (i < 262144) { src = x; ph = xh; pl = xl; off = i; }
    else {
        int j = i - 262144;
        int rg = j >> 14; off = j & 16383;
        if (rg == 0)      { src = wq; ph = wqh; pl = wql; }
        else if (rg == 1) { src = wk; ph = wkh; pl = wkl; }
        else if (rg == 2) { src = wv; ph = wvh; pl = wvl; }
        else              { src = wc; ph = wch; pl = wcl; }
    }
    float4 v = src[off];
    float vv[4] = {v.x, v.y, v.z, v.w};
    ushort4 hb, lb;
    unsigned short* hp = (unsigned short*)&hb;
    unsigned short* lp = (unsigned short*)&lb;
    for (int c = 0; c < 4; c++) {
        __hip_bfloat16 h = __float2bfloat16(vv[c]);
        hp[c] = *reinterpret_cast<unsigned short*>(&h);
        lp[c] = f2bf_bits(vv[c] - __bfloat162float(h));
    }
    int m = off >> 6, k = (off & 63) * 4;
    size_t fi = fragidx(m, k);          // divisible by 4
    ph[fi >> 2] = hb;
    pl[fi >> 2] = lb;
}

// ---------------- QKV projection: y = x @ W^T + b ----------------
// grid (NROW/64=64, 4, 3), block 256 (4 waves, 2x2 wave tiles of 32x32).
__global__ __launch_bounds__(256) void qkv_gemm(
    const __hip_bfloat16* __restrict__ xh, const __hip_bfloat16* __restrict__ xl,
    const __hip_bfloat16* __restrict__ w0h, const __hip_bfloat16* __restrict__ w0l,
    const __hip_bfloat16* __restrict__ w1h, const __hip_bfloat16* __restrict__ w1l,
    const __hip_bfloat16* __restrict__ w2h, const __hip_bfloat16* __restrict__ w2l,
    const float* __restrict__ bq, const float* __restrict__ bk, const float* __restrict__ bvv,
    __hip_bfloat16* __restrict__ Qf, __hip_bfloat16* __restrict__ Kf,
    __hip_bfloat16* __restrict__ Vf)
{
    int z = blockIdx.z;
    const __hip_bfloat16* wh = (z==0) ? w0h : (z==1) ? w1h : w2h;
    const __hip_bfloat16* wl = (z==0) ? w0l : (z==1) ? w1l : w2l;
    const float* bias = (z==0) ? bq : (z==1) ? bk : bvv;
    const float sv = (z==0) ? 0.17677669529663687f * 1.4426950408889634f : 1.0f;

    int tid = threadIdx.x;
    int w = tid >> 6, lid = tid & 63, quad = lid >> 4, l15 = lid & 15;
    int row0 = blockIdx.x * 64 + (w >> 1) * 32;
    int col0 = blockIdx.y * 64 + (w & 1) * 32;

    f32x4 acc[2][2] = {};
#pragma unroll
    for (int k0 = 0; k0 < 256; k0 += 32) {
        bf16x8 ah[2], al[2], bh[2], bl[2];
        for (int mi = 0; mi < 2; mi++) {
            size_t ro = (size_t)((row0 + mi * 16) >> 4) * 4096 + (k0 >> 5) * 512 + lid * 8;
            ah[mi] = *(const bf16x8*)(xh + ro);
            al[mi] = *(const bf16x8*)(xl + ro);
        }
        for (int ni = 0; ni < 2; ni++) {
            size_t co = (size_t)((col0 + ni * 16) >> 4) * 4096 + (k0 >> 5) * 512 + lid * 8;
            bh[ni] = *(const bf16x8*)(wh + co);
            bl[ni] = *(const bf16x8*)(wl + co);
        }
        for (int mi = 0; mi < 2; mi++)
            for (int ni = 0; ni < 2; ni++) {
                acc[mi][ni] = mfma_bf16(ah[mi], bh[ni], acc[mi][ni]);
                acc[mi][ni] = mfma_bf16(ah[mi], bl[ni], acc[mi][ni]);
                acc[mi][ni] = mfma_bf16(al[mi], bh[ni], acc[mi][ni]);
            }
    }
    for (int mi = 0; mi < 2; mi++)
        for (int ni = 0; ni < 2; ni++) {
            int col = col0 + ni * 16 + l15;       // D-layout: col = lane&15
            int h = col >> 5, dh = col & 31;
            float bvl = bias[col];
            for (int r = 0; r < 4; r++) {
                int row = row0 + mi * 16 + quad * 4 + r;  // D-layout: row = quad*4+r
                int b = row >> 11, s = row & 2047;
                __hip_bfloat16 o = __float2bfloat16((acc[mi][ni][r] + bvl) * sv);
                size_t bh_base = (size_t)(b * H_ + h) * (S_ * DH_);
                if (z == 2) {
                    int oo = s & 31;
                    int slot = ((oo & 15) >> 2) * 8 + ((oo >> 4) << 2) + (oo & 3);
                    Vf[bh_base + (s >> 5) * 1024 + (dh >> 4) * 512
                       + (slot >> 3) * 128 + (dh & 15) * 8 + (slot & 7)] = o;
                } else {
                    size_t idx = bh_base + (s >> 4) * 512 + (dh >> 3) * 128
                                 + (s & 15) * 8 + (dh & 7);
                    if (z == 0) Qf[idx] = o; else Kf[idx] = o;
                }
            }
        }
}

// ---------------- flash pass, fused combine ----------------
// flat grid 2048 blocks, block 256 = 4 waves. XCD-chunked swizzle: XCD x owns
// logical blocks [x*256,(x+1)*256) = 2 full (b,h) pairs -> K/V L2-resident.
// One q16-tile per BLOCK; wave w handles keys w*512..+511. Partial l / O'
// combined in LDS, normalized, written as fragment-linear hi/lo ctx + invL.
__global__ __launch_bounds__(256) void attn_flash(
    const __hip_bfloat16* __restrict__ Qf, const __hip_bfloat16* __restrict__ Kf,
    const __hip_bfloat16* __restrict__ Vf,
    __hip_bfloat16* __restrict__ cth, __hip_bfloat16* __restrict__ ctl,
    float* __restrict__ invL)
{
    __shared__ float sO[KSPLIT][16][33];   // +1 pad: avoid bank conflicts
    __shared__ float sL[KSPLIT][16];
    int f = blockIdx.x;
    int g = (f & 7) * 256 + (f >> 3);      // chunked XCD swizzle (bijective)
    int qt = g & 127;
    int h = (g >> 7) & 7;
    int b = g >> 10;
    int q0 = qt * 16;
    int tid = threadIdx.x, w = tid >> 6, lid = tid & 63, quad = lid >> 4, l15 = lid & 15;
    size_t bh_base = (size_t)(b * H_ + h) * (S_ * DH_);
    const __hip_bfloat16* Qp = Qf + bh_base + (q0 >> 4) * 512 + lid * 8;
    const __hip_bfloat16* Kp = Kf + bh_base + lid * 8;
    const __hip_bfloat16* Vp = Vf + bh_base + lid * 8;
    bf16x8 qf = *(const bf16x8*)Qp;                 // B: n=q (lane&15), k=dh
    f32x4 zacc = {};
    f32x4 oacc[2] = {};
    float lp0 = 0.f, lp1 = 0.f;

    int kbeg = w * KKEYS;
    // prologue prefetch: first k-tile
    bf16x8 kf0 = *(const bf16x8*)(Kp + (kbeg >> 4) * 512);
    bf16x8 kf1 = *(const bf16x8*)(Kp + (kbeg >> 4) * 512 + 512);
    bf16x8 vf0 = *(const bf16x8*)(Vp + (kbeg >> 5) * 1024);
    bf16x8 vf1 = *(const bf16x8*)(Vp + (kbeg >> 5) * 1024 + 512);

#pragma unroll 2
    for (int k0 = kbeg; k0 < kbeg + KKEYS; k0 += 32) {
        bf16x8 ck0 = kf0, ck1 = kf1, cv0 = vf0, cv1 = vf1;
        // prefetch next tile (wrap-clamped on last iter; value unused)
        int kn = (k0 + 32 < kbeg + KKEYS) ? k0 + 32 : kbeg;
        kf0 = *(const bf16x8*)(Kp + (kn >> 4) * 512);
        kf1 = *(const bf16x8*)(Kp + (kn >> 4) * 512 + 512);
        vf0 = *(const bf16x8*)(Vp + (kn >> 5) * 1024);
        vf1 = *(const bf16x8*)(Vp + (kn >> 5) * 1024 + 512);

        __builtin_amdgcn_s_setprio(1);
        f32x4 c0 = mfma_bf16(ck0, qf, zacc);   // keys k0+quad*4+r, q=l15
        f32x4 c1 = mfma_bf16(ck1, qf, zacc);   // keys k0+16+quad*4+r
        __builtin_amdgcn_s_setprio(0);
        float e0[4], e1[4];
        for (int r = 0; r < 4; r++) {
            e0[r] = fast_exp2(c0[r]);
            e1[r] = fast_exp2(c1[r]);
        }
        lp0 += e0[0] + e0[1] + e0[2] + e0[3];
        lp1 += e1[0] + e1[1] + e1[2] + e1[3];
        union { bf16x8 v; __hip_bfloat162 h2[4]; } pu;
        pu.h2[0] = __float22bfloat162_rn(make_float2(e0[0], e0[1]));
        pu.h2[1] = __float22bfloat162_rn(make_float2(e0[2], e0[3]));
        pu.h2[2] = __float22bfloat162_rn(make_float2(e1[0], e1[1]));
        pu.h2[3] = __float22bfloat162_rn(make_float2(e1[2], e1[3]));
        __builtin_amdgcn_s_setprio(1);
        oacc[0] = mfma_bf16(cv0, pu.v, oacc[0]);   // d 0..15
        oacc[1] = mfma_bf16(cv1, pu.v, oacc[1]);   // d 16..31
        __builtin_amdgcn_s_setprio(0);
    }
    float lp = lp0 + lp1;
    lp += __shfl_xor(lp, 16);
    lp += __shfl_xor(lp, 32);   // every lane: full 512-key row sum for q=l15

    // stash partials in LDS
    for (int r = 0; r < 4; r++) {
        sO[w][l15][quad * 4 + r]      = oacc[0][r];
        sO[w][l15][16 + quad * 4 + r] = oacc[1][r];
    }
    if (lid < 16) sL[w][lid] = lp;
    __syncthreads();

    // combine + normalize + write: 512 ctx elems / 256 threads = 2 each
    int d = tid & 31, q = tid >> 5;   // q in 0..7
#pragma unroll
    for (int qq = q; qq < 16; qq += 8) {
        float l = sL[0][qq] + sL[1][qq] + sL[2][qq] + sL[3][qq];
        float o = sO[0][qq][d] + sO[1][qq][d] + sO[2][qq][d] + sO[3][qq][d];
        float inv = 1.0f / l;
        float val = o * inv;
        size_t fi = fragidx(b * S_ + q0 + qq, h * DH_ + d);
        __hip_bfloat16 hv = __float2bfloat16(val);
        cth[fi] = hv;
        ctl[fi] = __float2bfloat16(val - __bfloat162float(hv));
        if (d == 0) invL[(b * H_ + h) * S_ + q0 + qq] = inv;
    }
}

// ---------------- merged: out projection (blocks 0..255) + attn write (256..2303) ----
// out_gemm first so its 256 blocks overlap the attn wave instead of the tail.
// attn blocks XCD-chunk-swizzled by (b,kx) so each XCD's K-chunk is L2-resident.
__global__ __launch_bounds__(256) void attn_out(
    const __hip_bfloat16* __restrict__ Qf, const __hip_bfloat16* __restrict__ Kf,
    const float* __restrict__ invL,
    const __hip_bfloat16* __restrict__ ch, const __hip_bfloat16* __restrict__ cl,
    const __hip_bfloat16* __restrict__ wh, const __hip_bfloat16* __restrict__ wl,
    const float* __restrict__ bias,
    float* __restrict__ attn, float* __restrict__ out)
{
    __shared__ float invbuf[H_ * 16];
    int bid = blockIdx.x;
    int tid = threadIdx.x, w = tid >> 6, lid = tid & 63, quad = lid >> 4, l15 = lid & 15;

    if (bid < 256) {
        // ---- out_gemm: out = ctx @ wc^T + bc (fp32 out), 2x2 wave tiles of 32x32 ----
        int row0 = (bid & 63) * 64 + (w >> 1) * 32;
        int col0 = (bid >> 6) * 64 + (w & 1) * 32;

        f32x4 acc[2][2] = {};
#pragma unroll
        for (int k0 = 0; k0 < 256; k0 += 32) {
            bf16x8 ah[2], al[2], bh[2], bl[2];
            for (int mi = 0; mi < 2; mi++) {
                size_t ro = (size_t)((row0 + mi * 16) >> 4) * 4096 + (k0 >> 5) * 512 + lid * 8;
                ah[mi] = *(const bf16x8*)(ch + ro);
                al[mi] = *(const bf16x8*)(cl + ro);
            }
            for (int ni = 0; ni < 2; ni++) {
                size_t co = (size_t)((col0 + ni * 16) >> 4) * 4096 + (k0 >> 5) * 512 + lid * 8;
                bh[ni] = *(const bf16x8*)(wh + co);
                bl[ni] = *(const bf16x8*)(wl + co);
            }
            for (int mi = 0; mi < 2; mi++)
                for (int ni = 0; ni < 2; ni++) {
                    acc[mi][ni] = mfma_bf16(ah[mi], bh[ni], acc[mi][ni]);
                    acc[mi][ni] = mfma_bf16(ah[mi], bl[ni], acc[mi][ni]);
                    acc[mi][ni] = mfma_bf16(al[mi], bh[ni], acc[mi][ni]);
                }
        }
        for (int mi = 0; mi < 2; mi++)
            for (int ni = 0; ni < 2; ni++) {
                int col = col0 + ni * 16 + l15;
                float bvl = bias[col];
                for (int r = 0; r < 4; r++) {
                    int row = row0 + mi * 16 + quad * 4 + r;
                    out[(size_t)row * 256 + col] = acc[mi][ni][r] + bvl;
                }
            }
    } else {
        // ---- attn write: head-mean probs, 16q x 256k per block ----
        int f2 = bid - 256;                       // 256 % 8 == 0: f2&7 preserves XCD
        int g = (f2 & 7) * 256 + (f2 >> 3);       // chunked XCD swizzle (bijective)
        int qy = g & 127, kx = (g >> 7) & 7, b = g >> 10;
        int q0 = qy * 16;
        int k0 = kx * 256 + w * 64;
        if (tid < 128) {
            int h = tid >> 4, r = tid & 15;
            invbuf[tid] = invL[(b * H_ + h) * S_ + q0 + r] * 0.125f;  // fold 1/H
        }
        __syncthreads();
        f32x4 zacc = {};
        float psum[4][4] = {};
        size_t bh0 = (size_t)b * H_ * (S_ * DH_);
        size_t qoff = (size_t)(q0 >> 4) * 512 + lid * 8;
        size_t koff = (size_t)(k0 >> 4) * 512 + lid * 8;

        // prologue prefetch: head 0
        bf16x8 qcur = *(const bf16x8*)(Qf + bh0 + qoff);
        bf16x8 kcur0 = *(const bf16x8*)(Kf + bh0 + koff);
        bf16x8 kcur1 = *(const bf16x8*)(Kf + bh0 + koff + 512);
        bf16x8 kcur2 = *(const bf16x8*)(Kf + bh0 + koff + 1024);
        bf16x8 kcur3 = *(const bf16x8*)(Kf + bh0 + koff + 1536);

#pragma unroll 2
        for (int h = 0; h < H_; h++) {
            int hn = (h < H_ - 1) ? h + 1 : h;
            size_t nb = bh0 + (size_t)hn * (S_ * DH_);
            bf16x8 qn = *(const bf16x8*)(Qf + nb + qoff);
            bf16x8 kn0 = *(const bf16x8*)(Kf + nb + koff);
            bf16x8 kn1 = *(const bf16x8*)(Kf + nb + koff + 512);
            bf16x8 kn2 = *(const bf16x8*)(Kf + nb + koff + 1024);
            bf16x8 kn3 = *(const bf16x8*)(Kf + nb + koff + 1536);

            float il[4];
            for (int r = 0; r < 4; r++) il[r] = invbuf[h * 16 + quad * 4 + r];

            __builtin_amdgcn_s_setprio(1);
            f32x4 c0 = mfma_bf16(qcur, kcur0, zacc);  // C: row=q (quad*4+r), col=key (l15)
            f32x4 c1 = mfma_bf16(qcur, kcur1, zacc);
            f32x4 c2 = mfma_bf16(qcur, kcur2, zacc);
            f32x4 c3 = mfma_bf16(qcur, kcur3, zacc);
            __builtin_amdgcn_s_setprio(0);
            for (int r = 0; r < 4; r++) {
                psum[0][r] += fast_exp2(c0[r]) * il[r];
                psum[1][r] += fast_exp2(c1[r]) * il[r];
                psum[2][r] += fast_exp2(c2[r]) * il[r];
                psum[3][r] += fast_exp2(c3[r]) * il[r];
            }
            qcur = qn;
            kcur0 = kn0; kcur1 = kn1; kcur2 = kn2; kcur3 = kn3;
        }
        for (int nt = 0; nt < 4; nt++)
            for (int r = 0; r < 4; r++)
                attn[(size_t)(b * S_ + q0 + quad * 4 + r) * S_ + k0 + nt * 16 + l15] =
                    psum[nt][r];
    }
}

extern "C" void kernel_launch(void* const* d_in, const int* in_sizes, int n_in,
                              void* d_out, int out_size, void* d_ws, size_t ws_size,
                              hipStream_t stream) {
    const float* x  = (const float*)d_in[0];
    const float* wq = (const float*)d_in[1];
    const float* bq = (const float*)d_in[2];
    const float* wk = (const float*)d_in[3];
    const float* bk = (const float*)d_in[4];
    const float* wv = (const float*)d_in[5];
    const float* bv = (const float*)d_in[6];
    const float* wc = (const float*)d_in[7];
    const float* bc = (const float*)d_in[8];

    char* ws = (char*)d_ws;
    const size_t MB = 1u << 20;
    const size_t KB128 = 128u * 1024u;
    __hip_bfloat16* xh  = (__hip_bfloat16*)(ws + 0 * MB);
    __hip_bfloat16* xl  = (__hip_bfloat16*)(ws + 2 * MB);
    __hip_bfloat16* wqh = (__hip_bfloat16*)(ws + 4 * MB + 0 * KB128);
    __hip_bfloat16* wql = (__hip_bfloat16*)(ws + 4 * MB + 1 * KB128);
    __hip_bfloat16* wkh = (__hip_bfloat16*)(ws + 4 * MB + 2 * KB128);
    __hip_bfloat16* wkl = (__hip_bfloat16*)(ws + 4 * MB + 3 * KB128);
    __hip_bfloat16* wvh = (__hip_bfloat16*)(ws + 4 * MB + 4 * KB128);
    __hip_bfloat16* wvl = (__hip_bfloat16*)(ws + 4 * MB + 5 * KB128);
    __hip_bfloat16* wch = (__hip_bfloat16*)(ws + 4 * MB + 6 * KB128);
    __hip_bfloat16* wcl = (__hip_bfloat16*)(ws + 4 * MB + 7 * KB128);
    __hip_bfloat16* Qfb = (__hip_bfloat16*)(ws + 5 * MB);
    __hip_bfloat16* Kfb = (__hip_bfloat16*)(ws + 7 * MB);
    __hip_bfloat16* Vfb = (__hip_bfloat16*)(ws + 9 * MB);
    __hip_bfloat16* cth = (__hip_bfloat16*)(ws + 11 * MB);
    __hip_bfloat16* ctl = (__hip_bfloat16*)(ws + 13 * MB);
    float* invL  = (float*)(ws + 15 * MB);                    // 128 KB

    float* outp  = (float*)d_out;
    float* attnp = outp + (size_t)NROW * D_;  // outputs concatenated: out, attention

    hipLaunchKernelGGL(split_all, dim3(1280), dim3(256), 0, stream,
                       (const float4*)x, (const float4*)wq, (const float4*)wk,
                       (const float4*)wv, (const float4*)wc,
                       (ushort4*)xh, (ushort4*)xl,
                       (ushort4*)wqh, (ushort4*)wql, (ushort4*)wkh, (ushort4*)wkl,
                       (ushort4*)wvh, (ushort4*)wvl, (ushort4*)wch, (ushort4*)wcl);

    hipLaunchKernelGGL(qkv_gemm, dim3(NROW / 64, 4, 3), dim3(256), 0, stream,
                       xh, xl, wqh, wql, wkh, wkl, wvh, wvl, bq, bk, bv, Qfb, Kfb, Vfb);

    hipLaunchKernelGGL(attn_flash, dim3(2048), dim3(256), 0, stream,
                       Qfb, Kfb, Vfb, cth, ctl, invL);

    hipLaunchKernelGGL(attn_out, dim3(256 + 2048), dim3(256), 0, stream,
                       Qfb, Kfb, invL, cth, ctl, wch, wcl, bc, attnp, outp);
}

// Round 4
// 127.035 us; speedup vs baseline: 1.1251x; 1.0564x over previous
//
#include <hip/hip_runtime.h>
#include <hip/hip_bf16.h>

// MHA fwd: B=2, S=2048, D=256, H=8, Dh=32.
// Outputs: out [2,2048,256] fp32, attn_mean [2,2048,2048] fp32 (concat in d_out).
//
// R11: q32 tiles in both S^2 kernels (register-level K reuse).
// Evidence ledger: traffic removal pays 1:1 (R9: -6.8us for 32MB); locality
// (R10), prefetch/setprio (R8), exp cost (R2/R7) all null. So: halve the
// VMEM work per score. Each flash wave now holds TWO q-frags (q32 block
// tile): 4 K/V loads feed 8 MFMAs instead of 4 (K/V traffic + load-issue
// per score halved; K/V re-read count per (b,h) drops 128->64 blocks).
// attn_write likewise: 6 loads per head feed 8 MFMAs (was 5 loads / 4).
// R8's null prefetch rotation dropped (frees VGPRs). Grids: flash 1024,
// attn_out 256+1024, XCD-chunked swizzle kept (free).

#define B_   2
#define S_   2048
#define D_   256
#define H_   8
#define DH_  32
#define NROW (B_*S_)      // 4096
#define KSPLIT 4
#define KKEYS (S_/KSPLIT) // 512

typedef __attribute__((ext_vector_type(8))) short bf16x8;  // 8 bf16 (4 VGPRs)
typedef __attribute__((ext_vector_type(4))) float f32x4;

__device__ __forceinline__ f32x4 mfma_bf16(bf16x8 a, bf16x8 b, f32x4 c) {
    return __builtin_amdgcn_mfma_f32_16x16x32_bf16(a, b, c, 0, 0, 0);
}

__device__ __forceinline__ float fast_exp2(float x) {
    return __builtin_amdgcn_exp2f(x);   // v_exp_f32
}

__device__ __forceinline__ unsigned short f2bf_bits(float v) {
    __hip_bfloat16 h = __float2bfloat16(v);
    return *reinterpret_cast<unsigned short*>(&h);
}

// fragment-linear index for a row-major [R x 256] matrix element (m, k)
__device__ __forceinline__ size_t fragidx(int m, int k) {
    return (size_t)(m >> 4) * 4096 + (k >> 5) * 512 + ((k >> 3) & 3) * 128
           + (m & 15) * 8 + (k & 7);
}

// ---------------- split fp32 -> (hi, lo) bf16, fragment-linear, one launch ----------------
__global__ void split_all(const float4* __restrict__ x,
                          const float4* __restrict__ wq, const float4* __restrict__ wk,
                          const float4* __restrict__ wv, const float4* __restrict__ wc,
                          ushort4* __restrict__ xh, ushort4* __restrict__ xl,
                          ushort4* __restrict__ wqh, ushort4* __restrict__ wql,
                          ushort4* __restrict__ wkh, ushort4* __restrict__ wkl,
                          ushort4* __restrict__ wvh, ushort4* __restrict__ wvl,
                          ushort4* __restrict__ wch, ushort4* __restrict__ wcl) {
    int i = blockIdx.x * 256 + threadIdx.x;   // total 327680 float4s
    const float4* src; ushort4 *ph, *pl; int off;
    if (i < 262144) { src = x; ph = xh; pl = xl; off = i; }
    else {
        int j = i - 262144;
        int rg = j >> 14; off = j & 16383;
        if (rg == 0)      { src = wq; ph = wqh; pl = wql; }
        else if (rg == 1) { src = wk; ph = wkh; pl = wkl; }
        else if (rg == 2) { src = wv; ph = wvh; pl = wvl; }
        else              { src = wc; ph = wch; pl = wcl; }
    }
    float4 v = src[off];
    float vv[4] = {v.x, v.y, v.z, v.w};
    ushort4 hb, lb;
    unsigned short* hp = (unsigned short*)&hb;
    unsigned short* lp = (unsigned short*)&lb;
    for (int c = 0; c < 4; c++) {
        __hip_bfloat16 h = __float2bfloat16(vv[c]);
        hp[c] = *reinterpret_cast<unsigned short*>(&h);
        lp[c] = f2bf_bits(vv[c] - __bfloat162float(h));
    }
    int m = off >> 6, k = (off & 63) * 4;
    size_t fi = fragidx(m, k);          // divisible by 4
    ph[fi >> 2] = hb;
    pl[fi >> 2] = lb;
}

// ---------------- QKV projection: y = x @ W^T + b ----------------
// grid (NROW/64=64, 4, 3), block 256 (4 waves, 2x2 wave tiles of 32x32).
__global__ __launch_bounds__(256) void qkv_gemm(
    const __hip_bfloat16* __restrict__ xh, const __hip_bfloat16* __restrict__ xl,
    const __hip_bfloat16* __restrict__ w0h, const __hip_bfloat16* __restrict__ w0l,
    const __hip_bfloat16* __restrict__ w1h, const __hip_bfloat16* __restrict__ w1l,
    const __hip_bfloat16* __restrict__ w2h, const __hip_bfloat16* __restrict__ w2l,
    const float* __restrict__ bq, const float* __restrict__ bk, const float* __restrict__ bvv,
    __hip_bfloat16* __restrict__ Qf, __hip_bfloat16* __restrict__ Kf,
    __hip_bfloat16* __restrict__ Vf)
{
    int z = blockIdx.z;
    const __hip_bfloat16* wh = (z==0) ? w0h : (z==1) ? w1h : w2h;
    const __hip_bfloat16* wl = (z==0) ? w0l : (z==1) ? w1l : w2l;
    const float* bias = (z==0) ? bq : (z==1) ? bk : bvv;
    const float sv = (z==0) ? 0.17677669529663687f * 1.4426950408889634f : 1.0f;

    int tid = threadIdx.x;
    int w = tid >> 6, lid = tid & 63, quad = lid >> 4, l15 = lid & 15;
    int row0 = blockIdx.x * 64 + (w >> 1) * 32;
    int col0 = blockIdx.y * 64 + (w & 1) * 32;

    f32x4 acc[2][2] = {};
#pragma unroll
    for (int k0 = 0; k0 < 256; k0 += 32) {
        bf16x8 ah[2], al[2], bh[2], bl[2];
        for (int mi = 0; mi < 2; mi++) {
            size_t ro = (size_t)((row0 + mi * 16) >> 4) * 4096 + (k0 >> 5) * 512 + lid * 8;
            ah[mi] = *(const bf16x8*)(xh + ro);
            al[mi] = *(const bf16x8*)(xl + ro);
        }
        for (int ni = 0; ni < 2; ni++) {
            size_t co = (size_t)((col0 + ni * 16) >> 4) * 4096 + (k0 >> 5) * 512 + lid * 8;
            bh[ni] = *(const bf16x8*)(wh + co);
            bl[ni] = *(const bf16x8*)(wl + co);
        }
        for (int mi = 0; mi < 2; mi++)
            for (int ni = 0; ni < 2; ni++) {
                acc[mi][ni] = mfma_bf16(ah[mi], bh[ni], acc[mi][ni]);
                acc[mi][ni] = mfma_bf16(ah[mi], bl[ni], acc[mi][ni]);
                acc[mi][ni] = mfma_bf16(al[mi], bh[ni], acc[mi][ni]);
            }
    }
    for (int mi = 0; mi < 2; mi++)
        for (int ni = 0; ni < 2; ni++) {
            int col = col0 + ni * 16 + l15;       // D-layout: col = lane&15
            int h = col >> 5, dh = col & 31;
            float bvl = bias[col];
            for (int r = 0; r < 4; r++) {
                int row = row0 + mi * 16 + quad * 4 + r;  // D-layout: row = quad*4+r
                int b = row >> 11, s = row & 2047;
                __hip_bfloat16 o = __float2bfloat16((acc[mi][ni][r] + bvl) * sv);
                size_t bh_base = (size_t)(b * H_ + h) * (S_ * DH_);
                if (z == 2) {
                    int oo = s & 31;
                    int slot = ((oo & 15) >> 2) * 8 + ((oo >> 4) << 2) + (oo & 3);
                    Vf[bh_base + (s >> 5) * 1024 + (dh >> 4) * 512
                       + (slot >> 3) * 128 + (dh & 15) * 8 + (slot & 7)] = o;
                } else {
                    size_t idx = bh_base + (s >> 4) * 512 + (dh >> 3) * 128
                                 + (s & 15) * 8 + (dh & 7);
                    if (z == 0) Qf[idx] = o; else Kf[idx] = o;
                }
            }
        }
}

// ---------------- flash pass, fused combine, q32 per block ----------------
// flat grid 1024 blocks, block 256 = 4 waves; XCD-chunked swizzle.
// Block = one q32-tile of (b,h); wave w covers keys w*512..+511 holding TWO
// q-frags so each K/V load feeds 2 QK + 2 PV MFMAs. Partials combined in
// LDS, normalized, written as fragment-linear hi/lo ctx + invL.
__global__ __launch_bounds__(256) void attn_flash(
    const __hip_bfloat16* __restrict__ Qf, const __hip_bfloat16* __restrict__ Kf,
    const __hip_bfloat16* __restrict__ Vf,
    __hip_bfloat16* __restrict__ cth, __hip_bfloat16* __restrict__ ctl,
    float* __restrict__ invL)
{
    __shared__ float sO[KSPLIT][32][33];   // +1 pad: avoid bank conflicts
    __shared__ float sL[KSPLIT][32];
    int f = blockIdx.x;
    int g = (f & 7) * 128 + (f >> 3);      // chunked XCD swizzle (bijective, 1024%8==0)
    int qt = g & 63;
    int h = (g >> 6) & 7;
    int b = g >> 9;
    int q0 = qt * 32;
    int tid = threadIdx.x, w = tid >> 6, lid = tid & 63, quad = lid >> 4, l15 = lid & 15;
    size_t bh_base = (size_t)(b * H_ + h) * (S_ * DH_);
    const __hip_bfloat16* Qp = Qf + bh_base + (q0 >> 4) * 512 + lid * 8;
    const __hip_bfloat16* Kp = Kf + bh_base + lid * 8;
    const __hip_bfloat16* Vp = Vf + bh_base + lid * 8;
    bf16x8 qfA = *(const bf16x8*)Qp;          // q-rows q0..q0+15   (B: n=q, k=dh)
    bf16x8 qfB = *(const bf16x8*)(Qp + 512);  // q-rows q0+16..q0+31
    f32x4 zacc = {};
    f32x4 oacc[2][2] = {};                    // [qgroup][dh-half]
    float lpA = 0.f, lpB = 0.f;

    int kbeg = w * KKEYS;
#pragma unroll 2
    for (int k0 = kbeg; k0 < kbeg + KKEYS; k0 += 32) {
        bf16x8 kf0 = *(const bf16x8*)(Kp + (k0 >> 4) * 512);
        bf16x8 kf1 = *(const bf16x8*)(Kp + (k0 >> 4) * 512 + 512);
        bf16x8 vf0 = *(const bf16x8*)(Vp + (k0 >> 5) * 1024);
        bf16x8 vf1 = *(const bf16x8*)(Vp + (k0 >> 5) * 1024 + 512);

        __builtin_amdgcn_s_setprio(1);
        f32x4 cA0 = mfma_bf16(kf0, qfA, zacc);   // keys k0+quad*4+r,    q=l15 (group A)
        f32x4 cA1 = mfma_bf16(kf1, qfA, zacc);   // keys k0+16+quad*4+r
        f32x4 cB0 = mfma_bf16(kf0, qfB, zacc);   // group B
        f32x4 cB1 = mfma_bf16(kf1, qfB, zacc);
        __builtin_amdgcn_s_setprio(0);
        float eA0[4], eA1[4], eB0[4], eB1[4];
        for (int r = 0; r < 4; r++) {
            eA0[r] = fast_exp2(cA0[r]);
            eA1[r] = fast_exp2(cA1[r]);
            eB0[r] = fast_exp2(cB0[r]);
            eB1[r] = fast_exp2(cB1[r]);
        }
        lpA += eA0[0] + eA0[1] + eA0[2] + eA0[3] + eA1[0] + eA1[1] + eA1[2] + eA1[3];
        lpB += eB0[0] + eB0[1] + eB0[2] + eB0[3] + eB1[0] + eB1[1] + eB1[2] + eB1[3];
        union { bf16x8 v; __hip_bfloat162 h2[4]; } puA, puB;
        puA.h2[0] = __float22bfloat162_rn(make_float2(eA0[0], eA0[1]));
        puA.h2[1] = __float22bfloat162_rn(make_float2(eA0[2], eA0[3]));
        puA.h2[2] = __float22bfloat162_rn(make_float2(eA1[0], eA1[1]));
        puA.h2[3] = __float22bfloat162_rn(make_float2(eA1[2], eA1[3]));
        puB.h2[0] = __float22bfloat162_rn(make_float2(eB0[0], eB0[1]));
        puB.h2[1] = __float22bfloat162_rn(make_float2(eB0[2], eB0[3]));
        puB.h2[2] = __float22bfloat162_rn(make_float2(eB1[0], eB1[1]));
        puB.h2[3] = __float22bfloat162_rn(make_float2(eB1[2], eB1[3]));
        __builtin_amdgcn_s_setprio(1);
        oacc[0][0] = mfma_bf16(vf0, puA.v, oacc[0][0]);   // d 0..15
        oacc[0][1] = mfma_bf16(vf1, puA.v, oacc[0][1]);   // d 16..31
        oacc[1][0] = mfma_bf16(vf0, puB.v, oacc[1][0]);
        oacc[1][1] = mfma_bf16(vf1, puB.v, oacc[1][1]);
        __builtin_amdgcn_s_setprio(0);
    }
    lpA += __shfl_xor(lpA, 16);
    lpA += __shfl_xor(lpA, 32);   // all lanes: full 512-key row sum for q=l15 (group A)
    lpB += __shfl_xor(lpB, 16);
    lpB += __shfl_xor(lpB, 32);

    // stash partials in LDS
    for (int qg = 0; qg < 2; qg++)
        for (int dh2 = 0; dh2 < 2; dh2++)
            for (int r = 0; r < 4; r++)
                sO[w][qg * 16 + l15][dh2 * 16 + quad * 4 + r] = oacc[qg][dh2][r];
    if (lid < 16) { sL[w][lid] = lpA; sL[w][16 + lid] = lpB; }
    __syncthreads();

    // combine + normalize + write: 1024 ctx elems / 256 threads = 4 each
    int d = tid & 31, q = tid >> 5;   // q in 0..7
#pragma unroll
    for (int qq = q; qq < 32; qq += 8) {
        float l = sL[0][qq] + sL[1][qq] + sL[2][qq] + sL[3][qq];
        float o = sO[0][qq][d] + sO[1][qq][d] + sO[2][qq][d] + sO[3][qq][d];
        float inv = 1.0f / l;
        float val = o * inv;
        size_t fi = fragidx(b * S_ + q0 + qq, h * DH_ + d);
        __hip_bfloat16 hv = __float2bfloat16(val);
        cth[fi] = hv;
        ctl[fi] = __float2bfloat16(val - __bfloat162float(hv));
        if (d == 0) invL[(b * H_ + h) * S_ + q0 + qq] = inv;
    }
}

// ---------------- merged: out projection (blocks 0..255) + attn write (256..1279) ----
// out_gemm first so its 256 blocks overlap the attn wave instead of the tail.
// attn blocks (q32 x 256k tiles) XCD-chunk-swizzled by (b,kx).
__global__ __launch_bounds__(256) void attn_out(
    const __hip_bfloat16* __restrict__ Qf, const __hip_bfloat16* __restrict__ Kf,
    const float* __restrict__ invL,
    const __hip_bfloat16* __restrict__ ch, const __hip_bfloat16* __restrict__ cl,
    const __hip_bfloat16* __restrict__ wh, const __hip_bfloat16* __restrict__ wl,
    const float* __restrict__ bias,
    float* __restrict__ attn, float* __restrict__ out)
{
    __shared__ float invbuf[H_ * 32];
    int bid = blockIdx.x;
    int tid = threadIdx.x, w = tid >> 6, lid = tid & 63, quad = lid >> 4, l15 = lid & 15;

    if (bid < 256) {
        // ---- out_gemm: out = ctx @ wc^T + bc (fp32 out), 2x2 wave tiles of 32x32 ----
        int row0 = (bid & 63) * 64 + (w >> 1) * 32;
        int col0 = (bid >> 6) * 64 + (w & 1) * 32;

        f32x4 acc[2][2] = {};
#pragma unroll
        for (int k0 = 0; k0 < 256; k0 += 32) {
            bf16x8 ah[2], al[2], bh[2], bl[2];
            for (int mi = 0; mi < 2; mi++) {
                size_t ro = (size_t)((row0 + mi * 16) >> 4) * 4096 + (k0 >> 5) * 512 + lid * 8;
                ah[mi] = *(const bf16x8*)(ch + ro);
                al[mi] = *(const bf16x8*)(cl + ro);
            }
            for (int ni = 0; ni < 2; ni++) {
                size_t co = (size_t)((col0 + ni * 16) >> 4) * 4096 + (k0 >> 5) * 512 + lid * 8;
                bh[ni] = *(const bf16x8*)(wh + co);
                bl[ni] = *(const bf16x8*)(wl + co);
            }
            for (int mi = 0; mi < 2; mi++)
                for (int ni = 0; ni < 2; ni++) {
                    acc[mi][ni] = mfma_bf16(ah[mi], bh[ni], acc[mi][ni]);
                    acc[mi][ni] = mfma_bf16(ah[mi], bl[ni], acc[mi][ni]);
                    acc[mi][ni] = mfma_bf16(al[mi], bh[ni], acc[mi][ni]);
                }
        }
        for (int mi = 0; mi < 2; mi++)
            for (int ni = 0; ni < 2; ni++) {
                int col = col0 + ni * 16 + l15;
                float bvl = bias[col];
                for (int r = 0; r < 4; r++) {
                    int row = row0 + mi * 16 + quad * 4 + r;
                    out[(size_t)row * 256 + col] = acc[mi][ni][r] + bvl;
                }
            }
    } else {
        // ---- attn write: head-mean probs, 32q x 256k per block ----
        int f2 = bid - 256;                       // 256 % 8 == 0: f2&7 preserves XCD
        int g = (f2 & 7) * 128 + (f2 >> 3);       // chunked XCD swizzle (bijective)
        int qy = g & 63, kx = (g >> 6) & 7, b = g >> 9;
        int q0 = qy * 32;
        int k0 = kx * 256 + w * 64;
        invbuf[tid] = invL[(b * H_ + (tid >> 5)) * S_ + q0 + (tid & 31)] * 0.125f; // fold 1/H
        __syncthreads();
        f32x4 zacc = {};
        float psum[2][4][4] = {};                 // [qgroup][ktile][r]
        size_t bh0 = (size_t)b * H_ * (S_ * DH_);
        size_t qoff = (size_t)(q0 >> 4) * 512 + lid * 8;
        size_t koff = (size_t)(k0 >> 4) * 512 + lid * 8;

#pragma unroll 2
        for (int h = 0; h < H_; h++) {
            size_t nb = bh0 + (size_t)h * (S_ * DH_);
            bf16x8 qfA = *(const bf16x8*)(Qf + nb + qoff);          // A: row=q (group A)
            bf16x8 qfB = *(const bf16x8*)(Qf + nb + qoff + 512);    // group B
            bf16x8 kf0 = *(const bf16x8*)(Kf + nb + koff);
            bf16x8 kf1 = *(const bf16x8*)(Kf + nb + koff + 512);
            bf16x8 kf2 = *(const bf16x8*)(Kf + nb + koff + 1024);
            bf16x8 kf3 = *(const bf16x8*)(Kf + nb + koff + 1536);

            float ilA[4], ilB[4];
            for (int r = 0; r < 4; r++) {
                ilA[r] = invbuf[h * 32 + quad * 4 + r];
                ilB[r] = invbuf[h * 32 + 16 + quad * 4 + r];
            }

            __builtin_amdgcn_s_setprio(1);
            f32x4 cA0 = mfma_bf16(qfA, kf0, zacc);  // C: row=q (quad*4+r), col=key (l15)
            f32x4 cA1 = mfma_bf16(qfA, kf1, zacc);
            f32x4 cA2 = mfma_bf16(qfA, kf2, zacc);
            f32x4 cA3 = mfma_bf16(qfA, kf3, zacc);
            f32x4 cB0 = mfma_bf16(qfB, kf0, zacc);
            f32x4 cB1 = mfma_bf16(qfB, kf1, zacc);
            f32x4 cB2 = mfma_bf16(qfB, kf2, zacc);
            f32x4 cB3 = mfma_bf16(qfB, kf3, zacc);
            __builtin_amdgcn_s_setprio(0);
            for (int r = 0; r < 4; r++) {
                psum[0][0][r] += fast_exp2(cA0[r]) * ilA[r];
                psum[0][1][r] += fast_exp2(cA1[r]) * ilA[r];
                psum[0][2][r] += fast_exp2(cA2[r]) * ilA[r];
                psum[0][3][r] += fast_exp2(cA3[r]) * ilA[r];
                psum[1][0][r] += fast_exp2(cB0[r]) * ilB[r];
                psum[1][1][r] += fast_exp2(cB1[r]) * ilB[r];
                psum[1][2][r] += fast_exp2(cB2[r]) * ilB[r];
                psum[1][3][r] += fast_exp2(cB3[r]) * ilB[r];
            }
        }
        for (int qg = 0; qg < 2; qg++)
            for (int nt = 0; nt < 4; nt++)
                for (int r = 0; r < 4; r++)
                    attn[(size_t)(b * S_ + q0 + qg * 16 + quad * 4 + r) * S_
                         + k0 + nt * 16 + l15] = psum[qg][nt][r];
    }
}

extern "C" void kernel_launch(void* const* d_in, const int* in_sizes, int n_in,
                              void* d_out, int out_size, void* d_ws, size_t ws_size,
                              hipStream_t stream) {
    const float* x  = (const float*)d_in[0];
    const float* wq = (const float*)d_in[1];
    const float* bq = (const float*)d_in[2];
    const float* wk = (const float*)d_in[3];
    const float* bk = (const float*)d_in[4];
    const float* wv = (const float*)d_in[5];
    const float* bv = (const float*)d_in[6];
    const float* wc = (const float*)d_in[7];
    const float* bc = (const float*)d_in[8];

    char* ws = (char*)d_ws;
    const size_t MB = 1u << 20;
    const size_t KB128 = 128u * 1024u;
    __hip_bfloat16* xh  = (__hip_bfloat16*)(ws + 0 * MB);
    __hip_bfloat16* xl  = (__hip_bfloat16*)(ws + 2 * MB);
    __hip_bfloat16* wqh = (__hip_bfloat16*)(ws + 4 * MB + 0 * KB128);
    __hip_bfloat16* wql = (__hip_bfloat16*)(ws + 4 * MB + 1 * KB128);
    __hip_bfloat16* wkh = (__hip_bfloat16*)(ws + 4 * MB + 2 * KB128);
    __hip_bfloat16* wkl = (__hip_bfloat16*)(ws + 4 * MB + 3 * KB128);
    __hip_bfloat16* wvh = (__hip_bfloat16*)(ws + 4 * MB + 4 * KB128);
    __hip_bfloat16* wvl = (__hip_bfloat16*)(ws + 4 * MB + 5 * KB128);
    __hip_bfloat16* wch = (__hip_bfloat16*)(ws + 4 * MB + 6 * KB128);
    __hip_bfloat16* wcl = (__hip_bfloat16*)(ws + 4 * MB + 7 * KB128);
    __hip_bfloat16* Qfb = (__hip_bfloat16*)(ws + 5 * MB);
    __hip_bfloat16* Kfb = (__hip_bfloat16*)(ws + 7 * MB);
    __hip_bfloat16* Vfb = (__hip_bfloat16*)(ws + 9 * MB);
    __hip_bfloat16* cth = (__hip_bfloat16*)(ws + 11 * MB);
    __hip_bfloat16* ctl = (__hip_bfloat16*)(ws + 13 * MB);
    float* invL  = (float*)(ws + 15 * MB);                    // 128 KB

    float* outp  = (float*)d_out;
    float* attnp = outp + (size_t)NROW * D_;  // outputs concatenated: out, attention

    hipLaunchKernelGGL(split_all, dim3(1280), dim3(256), 0, stream,
                       (const float4*)x, (const float4*)wq, (const float4*)wk,
                       (const float4*)wv, (const float4*)wc,
                       (ushort4*)xh, (ushort4*)xl,
                       (ushort4*)wqh, (ushort4*)wql, (ushort4*)wkh, (ushort4*)wkl,
                       (ushort4*)wvh, (ushort4*)wvl, (ushort4*)wch, (ushort4*)wcl);

    hipLaunchKernelGGL(qkv_gemm, dim3(NROW / 64, 4, 3), dim3(256), 0, stream,
                       xh, xl, wqh, wql, wkh, wkl, wvh, wvl, bq, bk, bv, Qfb, Kfb, Vfb);

    hipLaunchKernelGGL(attn_flash, dim3(1024), dim3(256), 0, stream,
                       Qfb, Kfb, Vfb, cth, ctl, invL);

    hipLaunchKernelGGL(attn_out, dim3(256 + 1024), dim3(256), 0, stream,
                       Qfb, Kfb, invL, cth, ctl, wch, wcl, bc, attnp, outp);
}